// Round 4
// baseline (158.951 us; speedup 1.0000x reference)
//
#include <hip/hip_runtime.h>
#include <hip/hip_bf16.h>
#include <stdint.h>

#define BB 8
#define LL 2048
#define DD 64

typedef short bf16x8 __attribute__((ext_vector_type(8)));  // 8 bf16 (4 VGPRs)
typedef float f32x4 __attribute__((ext_vector_type(4)));

// ---- bf16 packing helpers -------------------------------------------------
__device__ __forceinline__ unsigned pk2(float lo, float hi) {
    union { __hip_bfloat162 h; unsigned u; } c;
    c.h = __float22bfloat162_rn(make_float2(lo, hi));   // v_cvt_pk_bf16_f32
    return c.u;
}
__device__ __forceinline__ float4 ld4(const float* __restrict__ p) {
    return *reinterpret_cast<const float4*>(p);
}
__device__ __forceinline__ bf16x8 cvt8f(float4 a, float4 b) {
    union { bf16x8 v; unsigned u[4]; } r;
    r.u[0] = pk2(a.x, a.y); r.u[1] = pk2(a.z, a.w);
    r.u[2] = pk2(b.x, b.y); r.u[3] = pk2(b.z, b.w);
    return r.v;
}
// fallback-kernel helpers (round-2 proven)
__device__ __forceinline__ unsigned f2bf_u(float f) {
    union { float f; unsigned u; } v; v.f = f;
    return (v.u + 0x8000u) >> 16;
}
__device__ __forceinline__ bf16x8 cvt8(const float* __restrict__ p) {
    float4 a = ld4(p), b = ld4(p + 4);
    union { bf16x8 v; unsigned u[4]; } r;
    r.u[0] = f2bf_u(a.x) | (f2bf_u(a.y) << 16);
    r.u[1] = f2bf_u(a.z) | (f2bf_u(a.w) << 16);
    r.u[2] = f2bf_u(b.x) | (f2bf_u(b.y) << 16);
    r.u[3] = f2bf_u(b.z) | (f2bf_u(b.w) << 16);
    return r.v;
}

// ---- V transpose: V[b][k][d] -> VT[b][d][k] (fp32, into d_ws) -------------
__global__ __launch_bounds__(256) void transpose_v(const float* __restrict__ V,
                                                   float* __restrict__ VT) {
    __shared__ float t[64][65];
    const int b  = blockIdx.x >> 5;
    const int kt = (blockIdx.x & 31) << 6;
    {
        const int r  = threadIdx.x >> 2;
        const int cq = (threadIdx.x & 3) << 4;
        const float* src = V + ((size_t)(b * LL + kt + r)) * DD + cq;
        #pragma unroll
        for (int i = 0; i < 4; ++i) {
            float4 v = ld4(src + 4 * i);
            t[r][cq + 4 * i + 0] = v.x; t[r][cq + 4 * i + 1] = v.y;
            t[r][cq + 4 * i + 2] = v.z; t[r][cq + 4 * i + 3] = v.w;
        }
    }
    __syncthreads();
    {
        const int d  = threadIdx.x >> 2;
        const int kq = (threadIdx.x & 3) << 4;
        float* dst = VT + ((size_t)(b * DD + d)) * LL + kt + kq;
        #pragma unroll
        for (int u = 0; u < 4; ++u) {
            float4 v = { t[kq + 4 * u + 0][d], t[kq + 4 * u + 1][d],
                         t[kq + 4 * u + 2][d], t[kq + 4 * u + 3][d] };
            *reinterpret_cast<float4*>(dst + 4 * u) = v;
        }
    }
}

// ---- main attention kernel ------------------------------------------------
// Block = 512 thr = 8 waves. Each wave: ALL 64 q of the block (4 MFMA
// q-subtiles) x a 256-wide k-split (wave index = k-split). Grid = 8b x 32
// qtiles = 256 blocks -> 1 block/CU, 8 waves/CU (2/SIMD).
// Inner math identical to verified round-3 attn2: S^T = K*Q^T, exp+mask,
// cross-quad shuffle to PV A-frag, V^T B-frags. Partials combined via LDS
// float atomics (ds_add_f32) into one 64x68 Osum tile.
__global__ __launch_bounds__(512, 2) void attn3(
    const float* __restrict__ Q,
    const float* __restrict__ K,
    const float* __restrict__ VT,
    const int* __restrict__ qmask,
    const int* __restrict__ kmask,
    float* __restrict__ Out)
{
    const int tid  = threadIdx.x;
    const int wave = tid >> 6;         // k-split 0..7
    const int lane = tid & 63;
    const int ln   = lane & 15;
    const int quad = lane >> 4;

    const int b  = blockIdx.x >> 5;    // 8 batches
    const int q0 = (blockIdx.x & 31) << 6;   // 64 queries per block

    __shared__ float Osum[64][68];     // stride 68: 16B-aligned, 2-way banks
    __shared__ float Dsum[64];

    for (int i = tid; i < 64 * 68; i += 512) (&Osum[0][0])[i] = 0.f;
    if (tid < 64) Dsum[tid] = 0.f;

    // Q B-frags: qf[s][half], q = q0+16s+ln, d = half*32 + quad*8 + j
    bf16x8 qf[4][2];
    #pragma unroll
    for (int s = 0; s < 4; ++s) {
        const float* qp = Q + ((size_t)(b * LL + q0 + 16 * s + ln)) * DD + quad * 8;
        qf[s][0] = cvt8f(ld4(qp),      ld4(qp + 4));
        qf[s][1] = cvt8f(ld4(qp + 32), ld4(qp + 36));
    }
    __syncthreads();   // Osum/Dsum zeroed before any atomics

    const float* Kb  = K  + ((size_t)(b * LL) + ln) * DD + quad * 8;
    const float* Vb  = VT + ((size_t)(b * DD) + ln) * LL;
    const int*   kmb = kmask + b * LL;

    f32x4 Oacc[4][4];
    #pragma unroll
    for (int s = 0; s < 4; ++s)
        #pragma unroll
        for (int d = 0; d < 4; ++d) Oacc[s][d] = (f32x4){0.f, 0.f, 0.f, 0.f};
    float dsum[4] = {0.f, 0.f, 0.f, 0.f};

    const int src0 = ln + ((quad & 1) << 5);
    const int src1 = src0 + 16;
    const bool hi  = quad >= 2;

    const int kbeg = wave * (LL / 8);
    const int kend = kbeg + (LL / 8);

    #pragma unroll 2
    for (int k0 = kbeg; k0 < kend; k0 += 32) {
        // K A-frags: rows k0+16t+ln, d split in halves (direct global loads)
        const float* kp = Kb + (size_t)k0 * DD;
        bf16x8 kA[2][2];
        #pragma unroll
        for (int t = 0; t < 2; ++t) {
            kA[t][0] = cvt8f(ld4(kp + t * 16 * DD),      ld4(kp + t * 16 * DD + 4));
            kA[t][1] = cvt8f(ld4(kp + t * 16 * DD + 32), ld4(kp + t * 16 * DD + 36));
        }
        // V B-frags: V^T rows d = db*16+ln, cols k0+8quad+{0..7}
        const float* vp = Vb + k0 + 8 * quad;
        bf16x8 vf[4];
        #pragma unroll
        for (int db = 0; db < 4; ++db)
            vf[db] = cvt8f(ld4(vp + db * 16 * LL), ld4(vp + db * 16 * LL + 4));

        const int4 m0 = *reinterpret_cast<const int4*>(kmb + k0 + 4 * quad);
        const int4 m1 = *reinterpret_cast<const int4*>(kmb + k0 + 16 + 4 * quad);
        const float4 fm[2] = {
            { (float)m0.x, (float)m0.y, (float)m0.z, (float)m0.w },
            { (float)m1.x, (float)m1.y, (float)m1.z, (float)m1.w } };

        #pragma unroll
        for (int s = 0; s < 4; ++s) {
            // S^T tiles: lane holds P^T[k_local=16t+4quad+r][q=ln]
            unsigned w[2][2];
            #pragma unroll
            for (int t = 0; t < 2; ++t) {
                f32x4 acc = (f32x4){0.f, 0.f, 0.f, 0.f};
                acc = __builtin_amdgcn_mfma_f32_16x16x32_bf16(kA[t][0], qf[s][0], acc, 0, 0, 0);
                acc = __builtin_amdgcn_mfma_f32_16x16x32_bf16(kA[t][1], qf[s][1], acc, 0, 0, 0);
                float e0 = __expf(acc[0] * 0.125f) * fm[t].x;
                float e1 = __expf(acc[1] * 0.125f) * fm[t].y;
                float e2 = __expf(acc[2] * 0.125f) * fm[t].z;
                float e3 = __expf(acc[3] * 0.125f) * fm[t].w;
                dsum[s] += (e0 + e1) + (e2 + e3);
                w[t][0] = pk2(e0, e1);
                w[t][1] = pk2(e2, e3);
            }
            // P^T(C-layout) -> P(A-layout): cross-quad permutation (R3-verified)
            union { bf16x8 v; unsigned u[4]; } pf;
            {
                unsigned a0 = __shfl(w[0][0], src0), b0 = __shfl(w[1][0], src0);
                unsigned a1 = __shfl(w[0][1], src0), b1 = __shfl(w[1][1], src0);
                unsigned a2 = __shfl(w[0][0], src1), b2 = __shfl(w[1][0], src1);
                unsigned a3 = __shfl(w[0][1], src1), b3 = __shfl(w[1][1], src1);
                pf.u[0] = hi ? b0 : a0;
                pf.u[1] = hi ? b1 : a1;
                pf.u[2] = hi ? b2 : a2;
                pf.u[3] = hi ? b3 : a3;
            }
            #pragma unroll
            for (int db = 0; db < 4; ++db)
                Oacc[s][db] = __builtin_amdgcn_mfma_f32_16x16x32_bf16(pf.v, vf[db], Oacc[s][db], 0, 0, 0);
        }
    }

    // den: reduce across quads (q index = ln within each subtile)
    #pragma unroll
    for (int s = 0; s < 4; ++s) {
        float v = dsum[s];
        v += __shfl_xor(v, 16);
        v += __shfl_xor(v, 32);
        dsum[s] = v;
    }

    // combine k-splits: LDS float atomics (distinct (q,d) within a wave;
    // cross-wave collisions resolved by ds_add_f32)
    #pragma unroll
    for (int s = 0; s < 4; ++s)
        #pragma unroll
        for (int db = 0; db < 4; ++db)
            #pragma unroll
            for (int r = 0; r < 4; ++r)
                atomicAdd(&Osum[s * 16 + quad * 4 + r][db * 16 + ln], Oacc[s][db][r]);
    if (quad == 0) {
        #pragma unroll
        for (int s = 0; s < 4; ++s) atomicAdd(&Dsum[s * 16 + ln], dsum[s]);
    }
    __syncthreads();

    // normalize by max(den,1), apply q_mask, store fp32
    const int q  = tid >> 3;           // 0..63
    const int d0 = (tid & 7) << 3;     // 0..56
    float dn  = Dsum[q];
    float inv = 1.0f / fmaxf(dn, 1.0f);
    float sc  = qmask[b * LL + q0 + q] ? inv : 0.0f;
    f32x4 o0 = *reinterpret_cast<const f32x4*>(&Osum[q][d0])     * sc;
    f32x4 o1 = *reinterpret_cast<const f32x4*>(&Osum[q][d0 + 4]) * sc;
    float* op = Out + ((size_t)(b * LL + q0 + q)) * DD + d0;
    *reinterpret_cast<f32x4*>(op)     = o0;
    *reinterpret_cast<f32x4*>(op + 4) = o1;
}

// ---- fallback (round-2 kernel, used only if ws too small) -----------------
__global__ __launch_bounds__(256, 4) void attn_mfma(
    const float* __restrict__ Q, const float* __restrict__ K,
    const float* __restrict__ V, const int* __restrict__ qmask,
    const int* __restrict__ kmask, float* __restrict__ Out)
{
    const int tid  = threadIdx.x;
    const int wave = tid >> 6;
    const int lane = tid & 63;
    const int n    = lane & 15;
    const int quad = lane >> 4;
    const int bx = blockIdx.x;
    const int b  = bx >> 7;
    const int q0 = (bx & 127) << 4;
    __shared__ float Pl[4][576];
    __shared__ float Opart[4][16][68];
    __shared__ float Denp[4][16];
    const float* Qp = Q + ((size_t)(b * LL + q0 + n)) * DD + quad * 8;
    bf16x8 qf0 = cvt8(Qp);
    bf16x8 qf1 = cvt8(Qp + 32);
    const float* Kb = K + ((size_t)(b * LL) + n) * DD + quad * 8;
    const float* Vb = V + ((size_t)(b * LL) + quad * 8) * DD + n;
    const int* kmb = kmask + b * LL;
    f32x4 Oacc[4] = {{0,0,0,0},{0,0,0,0},{0,0,0,0},{0,0,0,0}};
    float den[4]  = {0.f, 0.f, 0.f, 0.f};
    float*       pw = &Pl[wave][144 * (n >> 3) + 36 * quad + (n & 7)];
    const float* pr = &Pl[wave][9 * lane];
    const int kbeg = wave * (LL / 4);
    const int kend = kbeg + (LL / 4);
    for (int k0 = kbeg; k0 < kend; k0 += 32) {
        const float* krow = Kb + (size_t)k0 * DD;
        bf16x8 kA0 = cvt8(krow);
        bf16x8 kA1 = cvt8(krow + 32);
        bf16x8 kB0 = cvt8(krow + 16 * DD);
        bf16x8 kB1 = cvt8(krow + 16 * DD + 32);
        f32x4 z = {0.f, 0.f, 0.f, 0.f};
        f32x4 S0 = __builtin_amdgcn_mfma_f32_16x16x32_bf16(qf0, kA0, z, 0, 0, 0);
        S0 = __builtin_amdgcn_mfma_f32_16x16x32_bf16(qf1, kA1, S0, 0, 0, 0);
        f32x4 S1 = __builtin_amdgcn_mfma_f32_16x16x32_bf16(qf0, kB0, z, 0, 0, 0);
        S1 = __builtin_amdgcn_mfma_f32_16x16x32_bf16(qf1, kB1, S1, 0, 0, 0);
        float km0 = (float)kmb[k0 + n];
        float km1 = (float)kmb[k0 + 16 + n];
        #pragma unroll
        for (int r = 0; r < 4; ++r) {
            float e0 = __expf(S0[r] * 0.125f) * km0;
            float e1 = __expf(S1[r] * 0.125f) * km1;
            den[r] += e0 + e1;
            pw[9 * r]       = e0;
            pw[288 + 9 * r] = e1;
        }
        __builtin_amdgcn_wave_barrier();
        float pv[8];
        #pragma unroll
        for (int j = 0; j < 8; ++j) pv[j] = pr[j];
        __builtin_amdgcn_wave_barrier();
        union { bf16x8 v; unsigned u[4]; } pf;
        #pragma unroll
        for (int j = 0; j < 4; ++j)
            pf.u[j] = f2bf_u(pv[2 * j]) | (f2bf_u(pv[2 * j + 1]) << 16);
        const float* vrow = Vb + (size_t)k0 * DD;
        #pragma unroll
        for (int db = 0; db < 4; ++db) {
            union { bf16x8 v; unsigned u[4]; } vfr;
            #pragma unroll
            for (int jj = 0; jj < 4; ++jj) {
                unsigned lo  = f2bf_u(vrow[(2 * jj) * DD + db * 16]);
                unsigned hi2 = f2bf_u(vrow[(2 * jj + 1) * DD + db * 16]);
                vfr.u[jj] = lo | (hi2 << 16);
            }
            Oacc[db] = __builtin_amdgcn_mfma_f32_16x16x32_bf16(pf.v, vfr.v, Oacc[db], 0, 0, 0);
        }
    }
    #pragma unroll
    for (int r = 0; r < 4; ++r) {
        float v = den[r];
        v += __shfl_xor(v, 1); v += __shfl_xor(v, 2);
        v += __shfl_xor(v, 4); v += __shfl_xor(v, 8);
        den[r] = v;
    }
    #pragma unroll
    for (int db = 0; db < 4; ++db)
        #pragma unroll
        for (int r = 0; r < 4; ++r)
            Opart[wave][quad * 4 + r][db * 16 + n] = Oacc[db][r];
    if (n == 0) {
        #pragma unroll
        for (int r = 0; r < 4; ++r) Denp[wave][quad * 4 + r] = den[r];
    }
    __syncthreads();
    const int q  = tid >> 4;
    const int d0 = (tid & 15) * 4;
    f32x4 sum = *reinterpret_cast<const f32x4*>(&Opart[0][q][d0]);
    sum += *reinterpret_cast<const f32x4*>(&Opart[1][q][d0]);
    sum += *reinterpret_cast<const f32x4*>(&Opart[2][q][d0]);
    sum += *reinterpret_cast<const f32x4*>(&Opart[3][q][d0]);
    float dn  = Denp[0][q] + Denp[1][q] + Denp[2][q] + Denp[3][q];
    float inv = 1.0f / fmaxf(dn, 1.0f);
    float s   = qmask[b * LL + q0 + q] ? inv : 0.0f;
    f32x4 o   = sum * s;
    float* op = Out + ((size_t)(b * LL + q0 + q)) * DD + d0;
    *reinterpret_cast<f32x4*>(op) = o;
}

extern "C" void kernel_launch(void* const* d_in, const int* in_sizes, int n_in,
                              void* d_out, int out_size, void* d_ws, size_t ws_size,
                              hipStream_t stream) {
    (void)in_sizes; (void)n_in; (void)out_size;
    const float* Q  = (const float*)d_in[0];
    const float* K  = (const float*)d_in[1];
    const float* V  = (const float*)d_in[2];
    const int* qm   = (const int*)d_in[3];
    const int* km   = (const int*)d_in[4];
    float* Out      = (float*)d_out;

    const size_t vt_bytes = (size_t)BB * LL * DD * sizeof(float);  // 4 MiB
    if (ws_size >= vt_bytes && d_ws != nullptr) {
        float* VT = (float*)d_ws;
        transpose_v<<<dim3(BB * (LL / 64)), dim3(256), 0, stream>>>(V, VT);
        attn3<<<dim3(BB * (LL / 64)), dim3(512), 0, stream>>>(Q, K, VT, qm, km, Out);
    } else {
        attn_mfma<<<dim3(BB * (LL / 16)), dim3(256), 0, stream>>>(Q, K, V, qm, km, Out);
    }
}

// Round 5
// 126.332 us; speedup vs baseline: 1.2582x; 1.2582x over previous
//
#include <hip/hip_runtime.h>
#include <hip/hip_bf16.h>
#include <stdint.h>

#define BB 8
#define LL 2048
#define DD 64

typedef short bf16x8 __attribute__((ext_vector_type(8)));  // 8 bf16 (4 VGPRs)
typedef float f32x4 __attribute__((ext_vector_type(4)));
typedef unsigned short ushort_t;

// ---- helpers --------------------------------------------------------------
__device__ __forceinline__ unsigned pk2(float lo, float hi) {
    union { __hip_bfloat162 h; unsigned u; } c;
    c.h = __float22bfloat162_rn(make_float2(lo, hi));   // v_cvt_pk_bf16_f32
    return c.u;
}
__device__ __forceinline__ float4 ld4(const float* __restrict__ p) {
    return *reinterpret_cast<const float4*>(p);
}
__device__ __forceinline__ bf16x8 cvt8f(float4 a, float4 b) {
    union { bf16x8 v; unsigned u[4]; } r;
    r.u[0] = pk2(a.x, a.y); r.u[1] = pk2(a.z, a.w);
    r.u[2] = pk2(b.x, b.y); r.u[3] = pk2(b.z, b.w);
    return r.v;
}
__device__ __forceinline__ bf16x8 asbf(uint4 u) {
    union { uint4 q; bf16x8 v; } c; c.q = u; return c.v;
}
// fallback-kernel helpers (round-2 proven)
__device__ __forceinline__ unsigned f2bf_u(float f) {
    union { float f; unsigned u; } v; v.f = f;
    return (v.u + 0x8000u) >> 16;
}
__device__ __forceinline__ bf16x8 cvt8(const float* __restrict__ p) {
    float4 a = ld4(p), b = ld4(p + 4);
    union { bf16x8 v; unsigned u[4]; } r;
    r.u[0] = f2bf_u(a.x) | (f2bf_u(a.y) << 16);
    r.u[1] = f2bf_u(a.z) | (f2bf_u(a.w) << 16);
    r.u[2] = f2bf_u(b.x) | (f2bf_u(b.y) << 16);
    r.u[3] = f2bf_u(b.z) | (f2bf_u(b.w) << 16);
    return r.v;
}

// ---- prep 1: K fp32 [b][k][d] -> bf16 same layout -------------------------
__global__ __launch_bounds__(256) void pack_k_bf16(const float* __restrict__ K,
                                                   ushort_t* __restrict__ Kb) {
    size_t i = ((size_t)blockIdx.x * 256 + threadIdx.x) * 8;
    float4 a = ld4(K + i), b = ld4(K + i + 4);
    uint4 o = { pk2(a.x, a.y), pk2(a.z, a.w), pk2(b.x, b.y), pk2(b.z, b.w) };
    *reinterpret_cast<uint4*>(Kb + i) = o;
}

// ---- prep 2: V fp32 [b][k][d] -> bf16 transposed [b][d][k] ----------------
__global__ __launch_bounds__(256) void transpose_v_bf(const float* __restrict__ V,
                                                      ushort_t* __restrict__ VT) {
    __shared__ float t[64][65];
    const int b  = blockIdx.x >> 5;
    const int kt = (blockIdx.x & 31) << 6;
    {
        const int r  = threadIdx.x >> 2;
        const int cq = (threadIdx.x & 3) << 4;
        const float* src = V + ((size_t)(b * LL + kt + r)) * DD + cq;
        #pragma unroll
        for (int i = 0; i < 4; ++i) {
            float4 v = ld4(src + 4 * i);
            t[r][cq + 4 * i + 0] = v.x; t[r][cq + 4 * i + 1] = v.y;
            t[r][cq + 4 * i + 2] = v.z; t[r][cq + 4 * i + 3] = v.w;
        }
    }
    __syncthreads();
    {
        const int d  = threadIdx.x >> 2;
        const int kq = (threadIdx.x & 3) << 4;
        ushort_t* dst = VT + ((size_t)(b * DD + d)) * LL + kt + kq;
        #pragma unroll
        for (int u = 0; u < 2; ++u) {
            uint4 o;
            o.x = pk2(t[kq + 8 * u + 0][d], t[kq + 8 * u + 1][d]);
            o.y = pk2(t[kq + 8 * u + 2][d], t[kq + 8 * u + 3][d]);
            o.z = pk2(t[kq + 8 * u + 4][d], t[kq + 8 * u + 5][d]);
            o.w = pk2(t[kq + 8 * u + 6][d], t[kq + 8 * u + 7][d]);
            *reinterpret_cast<uint4*>(dst + 8 * u) = o;
        }
    }
}

// ---- main attention kernel ------------------------------------------------
// Block = 256 thr = 4 waves; wave = k-split (512 k each); 32 q per block
// (2 MFMA q-subtiles, all waves same q). Grid = 8b x 64 = 512 blocks
// (2 blocks/CU). K/V pre-packed bf16 so global loads ARE the fragments:
// 10 VMEM per 32k chunk, explicitly double-staged so next chunk's loads
// stay in flight (vmcnt(10)) across current chunk's compute.
// Inner math identical to verified R3/R4: S^T = K*Q^T, exp+mask,
// cross-quad shuffle to PV A-frag. Epilogue: LDS-atomic combine (R4).
__global__ __launch_bounds__(256, 2) void attn4(
    const float* __restrict__ Q,
    const ushort_t* __restrict__ Kbf,
    const ushort_t* __restrict__ VTb,
    const int* __restrict__ qmask,
    const int* __restrict__ kmask,
    float* __restrict__ Out)
{
    const int tid  = threadIdx.x;
    const int wave = tid >> 6;         // k-split 0..3
    const int lane = tid & 63;
    const int ln   = lane & 15;
    const int quad = lane >> 4;

    const int b  = blockIdx.x >> 6;          // 8 batches
    const int q0 = (blockIdx.x & 63) << 5;   // 32 q per block

    __shared__ float Osum[32][68];
    __shared__ float Dsum[32];
    for (int i = tid; i < 32 * 68; i += 256) (&Osum[0][0])[i] = 0.f;
    if (tid < 32) Dsum[tid] = 0.f;

    // Q B-frags: q = q0+16s+ln, d = half*32 + quad*8 + j
    bf16x8 qf[2][2];
    #pragma unroll
    for (int s = 0; s < 2; ++s) {
        const float* qp = Q + ((size_t)(b * LL + q0 + 16 * s + ln)) * DD + quad * 8;
        qf[s][0] = cvt8f(ld4(qp),      ld4(qp + 4));
        qf[s][1] = cvt8f(ld4(qp + 32), ld4(qp + 36));
    }
    __syncthreads();   // Osum/Dsum zeroed before any atomics

    const ushort_t* Kb  = Kbf + ((size_t)(b * LL) + ln) * DD + quad * 8;
    const ushort_t* Vb  = VTb + ((size_t)(b * DD) + ln) * LL;
    const int*      kmb = kmask + b * LL;

    f32x4 Oacc[2][4];
    #pragma unroll
    for (int s = 0; s < 2; ++s)
        #pragma unroll
        for (int d = 0; d < 4; ++d) Oacc[s][d] = (f32x4){0.f, 0.f, 0.f, 0.f};
    float dsum[2] = {0.f, 0.f};

    const int src0 = ln + ((quad & 1) << 5);
    const int src1 = src0 + 16;
    const bool hi  = quad >= 2;

    const int kbeg = wave * (LL / 4);

    // two explicit stages, constant-indexed (SROA-friendly, no copies)
    uint4 ka[2][4]; uint4 va[2][4]; int4 ma[2][2];

    auto LOADST = [&](int st, int kk) {
        const ushort_t* kp = Kb + (size_t)kk * DD;
        ka[st][0] = *reinterpret_cast<const uint4*>(kp);                 // t0 d0-31
        ka[st][1] = *reinterpret_cast<const uint4*>(kp + 32);            // t0 d32-63
        ka[st][2] = *reinterpret_cast<const uint4*>(kp + 16 * DD);       // t1 d0-31
        ka[st][3] = *reinterpret_cast<const uint4*>(kp + 16 * DD + 32);  // t1 d32-63
        const ushort_t* vp = Vb + kk + 8 * quad;
        va[st][0] = *reinterpret_cast<const uint4*>(vp);
        va[st][1] = *reinterpret_cast<const uint4*>(vp + 16 * LL);
        va[st][2] = *reinterpret_cast<const uint4*>(vp + 32 * LL);
        va[st][3] = *reinterpret_cast<const uint4*>(vp + 48 * LL);
        ma[st][0] = *reinterpret_cast<const int4*>(kmb + kk + 4 * quad);
        ma[st][1] = *reinterpret_cast<const int4*>(kmb + kk + 16 + 4 * quad);
    };

    auto COMP = [&](int st) {
        const float4 fm[2] = {
            { (float)ma[st][0].x, (float)ma[st][0].y, (float)ma[st][0].z, (float)ma[st][0].w },
            { (float)ma[st][1].x, (float)ma[st][1].y, (float)ma[st][1].z, (float)ma[st][1].w } };
        #pragma unroll
        for (int s = 0; s < 2; ++s) {
            unsigned w[2][2];
            #pragma unroll
            for (int t = 0; t < 2; ++t) {
                f32x4 acc = (f32x4){0.f, 0.f, 0.f, 0.f};
                acc = __builtin_amdgcn_mfma_f32_16x16x32_bf16(asbf(ka[st][t * 2 + 0]), qf[s][0], acc, 0, 0, 0);
                acc = __builtin_amdgcn_mfma_f32_16x16x32_bf16(asbf(ka[st][t * 2 + 1]), qf[s][1], acc, 0, 0, 0);
                float e0 = __expf(acc[0] * 0.125f) * fm[t].x;
                float e1 = __expf(acc[1] * 0.125f) * fm[t].y;
                float e2 = __expf(acc[2] * 0.125f) * fm[t].z;
                float e3 = __expf(acc[3] * 0.125f) * fm[t].w;
                dsum[s] += (e0 + e1) + (e2 + e3);
                w[t][0] = pk2(e0, e1);
                w[t][1] = pk2(e2, e3);
            }
            union { bf16x8 v; unsigned u[4]; } pf;
            {
                unsigned a0 = __shfl(w[0][0], src0), b0 = __shfl(w[1][0], src0);
                unsigned a1 = __shfl(w[0][1], src0), b1 = __shfl(w[1][1], src0);
                unsigned a2 = __shfl(w[0][0], src1), b2 = __shfl(w[1][0], src1);
                unsigned a3 = __shfl(w[0][1], src1), b3 = __shfl(w[1][1], src1);
                pf.u[0] = hi ? b0 : a0;
                pf.u[1] = hi ? b1 : a1;
                pf.u[2] = hi ? b2 : a2;
                pf.u[3] = hi ? b3 : a3;
            }
            #pragma unroll
            for (int db = 0; db < 4; ++db)
                Oacc[s][db] = __builtin_amdgcn_mfma_f32_16x16x32_bf16(pf.v, asbf(va[st][db]), Oacc[s][db], 0, 0, 0);
        }
    };

    LOADST(0, kbeg);
    for (int i = 0; i < 16; i += 2) {   // 16 chunks of 32 k
        LOADST(1, kbeg + ((i + 1) & 15) * 32);
        COMP(0);
        LOADST(0, kbeg + ((i + 2) & 15) * 32);
        COMP(1);
    }

    // den: reduce across quads (q index = ln within each subtile)
    #pragma unroll
    for (int s = 0; s < 2; ++s) {
        float v = dsum[s];
        v += __shfl_xor(v, 16);
        v += __shfl_xor(v, 32);
        dsum[s] = v;
    }

    // combine k-splits via LDS float atomics (R4-verified)
    #pragma unroll
    for (int s = 0; s < 2; ++s)
        #pragma unroll
        for (int db = 0; db < 4; ++db)
            #pragma unroll
            for (int r = 0; r < 4; ++r)
                atomicAdd(&Osum[s * 16 + quad * 4 + r][db * 16 + ln], Oacc[s][db][r]);
    if (quad == 0) {
        #pragma unroll
        for (int s = 0; s < 2; ++s) atomicAdd(&Dsum[s * 16 + ln], dsum[s]);
    }
    __syncthreads();

    // normalize by max(den,1), apply q_mask, store fp32
    const int q  = tid >> 3;           // 0..31
    const int d0 = (tid & 7) << 3;     // 0..56
    float dn  = Dsum[q];
    float inv = 1.0f / fmaxf(dn, 1.0f);
    float sc  = qmask[b * LL + q0 + q] ? inv : 0.0f;
    f32x4 o0 = *reinterpret_cast<const f32x4*>(&Osum[q][d0])     * sc;
    f32x4 o1 = *reinterpret_cast<const f32x4*>(&Osum[q][d0 + 4]) * sc;
    float* op = Out + ((size_t)(b * LL + q0 + q)) * DD + d0;
    *reinterpret_cast<f32x4*>(op)     = o0;
    *reinterpret_cast<f32x4*>(op + 4) = o1;
}

// ---- fallback (round-2 kernel, used only if ws too small) -----------------
__global__ __launch_bounds__(256, 4) void attn_mfma(
    const float* __restrict__ Q, const float* __restrict__ K,
    const float* __restrict__ V, const int* __restrict__ qmask,
    const int* __restrict__ kmask, float* __restrict__ Out)
{
    const int tid  = threadIdx.x;
    const int wave = tid >> 6;
    const int lane = tid & 63;
    const int n    = lane & 15;
    const int quad = lane >> 4;
    const int bx = blockIdx.x;
    const int b  = bx >> 7;
    const int q0 = (bx & 127) << 4;
    __shared__ float Pl[4][576];
    __shared__ float Opart[4][16][68];
    __shared__ float Denp[4][16];
    const float* Qp = Q + ((size_t)(b * LL + q0 + n)) * DD + quad * 8;
    bf16x8 qf0 = cvt8(Qp);
    bf16x8 qf1 = cvt8(Qp + 32);
    const float* Kb = K + ((size_t)(b * LL) + n) * DD + quad * 8;
    const float* Vb = V + ((size_t)(b * LL) + quad * 8) * DD + n;
    const int* kmb = kmask + b * LL;
    f32x4 Oacc[4] = {{0,0,0,0},{0,0,0,0},{0,0,0,0},{0,0,0,0}};
    float den[4]  = {0.f, 0.f, 0.f, 0.f};
    float*       pw = &Pl[wave][144 * (n >> 3) + 36 * quad + (n & 7)];
    const float* pr = &Pl[wave][9 * lane];
    const int kbeg = wave * (LL / 4);
    const int kend = kbeg + (LL / 4);
    for (int k0 = kbeg; k0 < kend; k0 += 32) {
        const float* krow = Kb + (size_t)k0 * DD;
        bf16x8 kA0 = cvt8(krow);
        bf16x8 kA1 = cvt8(krow + 32);
        bf16x8 kB0 = cvt8(krow + 16 * DD);
        bf16x8 kB1 = cvt8(krow + 16 * DD + 32);
        f32x4 z = {0.f, 0.f, 0.f, 0.f};
        f32x4 S0 = __builtin_amdgcn_mfma_f32_16x16x32_bf16(qf0, kA0, z, 0, 0, 0);
        S0 = __builtin_amdgcn_mfma_f32_16x16x32_bf16(qf1, kA1, S0, 0, 0, 0);
        f32x4 S1 = __builtin_amdgcn_mfma_f32_16x16x32_bf16(qf0, kB0, z, 0, 0, 0);
        S1 = __builtin_amdgcn_mfma_f32_16x16x32_bf16(qf1, kB1, S1, 0, 0, 0);
        float km0 = (float)kmb[k0 + n];
        float km1 = (float)kmb[k0 + 16 + n];
        #pragma unroll
        for (int r = 0; r < 4; ++r) {
            float e0 = __expf(S0[r] * 0.125f) * km0;
            float e1 = __expf(S1[r] * 0.125f) * km1;
            den[r] += e0 + e1;
            pw[9 * r]       = e0;
            pw[288 + 9 * r] = e1;
        }
        __builtin_amdgcn_wave_barrier();
        float pv[8];
        #pragma unroll
        for (int j = 0; j < 8; ++j) pv[j] = pr[j];
        __builtin_amdgcn_wave_barrier();
        union { bf16x8 v; unsigned u[4]; } pf;
        #pragma unroll
        for (int j = 0; j < 4; ++j)
            pf.u[j] = f2bf_u(pv[2 * j]) | (f2bf_u(pv[2 * j + 1]) << 16);
        const float* vrow = Vb + (size_t)k0 * DD;
        #pragma unroll
        for (int db = 0; db < 4; ++db) {
            union { bf16x8 v; unsigned u[4]; } vfr;
            #pragma unroll
            for (int jj = 0; jj < 4; ++jj) {
                unsigned lo  = f2bf_u(vrow[(2 * jj) * DD + db * 16]);
                unsigned hi2 = f2bf_u(vrow[(2 * jj + 1) * DD + db * 16]);
                vfr.u[jj] = lo | (hi2 << 16);
            }
            Oacc[db] = __builtin_amdgcn_mfma_f32_16x16x32_bf16(pf.v, vfr.v, Oacc[db], 0, 0, 0);
        }
    }
    #pragma unroll
    for (int r = 0; r < 4; ++r) {
        float v = den[r];
        v += __shfl_xor(v, 1); v += __shfl_xor(v, 2);
        v += __shfl_xor(v, 4); v += __shfl_xor(v, 8);
        den[r] = v;
    }
    #pragma unroll
    for (int db = 0; db < 4; ++db)
        #pragma unroll
        for (int r = 0; r < 4; ++r)
            Opart[wave][quad * 4 + r][db * 16 + n] = Oacc[db][r];
    if (n == 0) {
        #pragma unroll
        for (int r = 0; r < 4; ++r) Denp[wave][quad * 4 + r] = den[r];
    }
    __syncthreads();
    const int q  = tid >> 4;
    const int d0 = (tid & 15) * 4;
    f32x4 sum = *reinterpret_cast<const f32x4*>(&Opart[0][q][d0]);
    sum += *reinterpret_cast<const f32x4*>(&Opart[1][q][d0]);
    sum += *reinterpret_cast<const f32x4*>(&Opart[2][q][d0]);
    sum += *reinterpret_cast<const f32x4*>(&Opart[3][q][d0]);
    float dn  = Denp[0][q] + Denp[1][q] + Denp[2][q] + Denp[3][q];
    float inv = 1.0f / fmaxf(dn, 1.0f);
    float s   = qmask[b * LL + q0 + q] ? inv : 0.0f;
    f32x4 o   = sum * s;
    float* op = Out + ((size_t)(b * LL + q0 + q)) * DD + d0;
    *reinterpret_cast<f32x4*>(op) = o;
}

extern "C" void kernel_launch(void* const* d_in, const int* in_sizes, int n_in,
                              void* d_out, int out_size, void* d_ws, size_t ws_size,
                              hipStream_t stream) {
    (void)in_sizes; (void)n_in; (void)out_size;
    const float* Q  = (const float*)d_in[0];
    const float* K  = (const float*)d_in[1];
    const float* V  = (const float*)d_in[2];
    const int* qm   = (const int*)d_in[3];
    const int* km   = (const int*)d_in[4];
    float* Out      = (float*)d_out;

    const size_t elems    = (size_t)BB * LL * DD;            // 1,048,576
    const size_t ws_need  = elems * 2 * sizeof(ushort_t);    // 4 MiB
    if (ws_size >= ws_need && d_ws != nullptr) {
        ushort_t* Kbf = (ushort_t*)d_ws;
        ushort_t* VTb = Kbf + elems;
        pack_k_bf16   <<<dim3(elems / (256 * 8)), dim3(256), 0, stream>>>(K, Kbf);
        transpose_v_bf<<<dim3(BB * (LL / 64)),    dim3(256), 0, stream>>>(V, VTb);
        attn4<<<dim3(BB * (LL / 32)), dim3(256), 0, stream>>>(Q, Kbf, VTb, qm, km, Out);
    } else {
        attn_mfma<<<dim3(BB * (LL / 16)), dim3(256), 0, stream>>>(Q, K, V, qm, km, Out);
    }
}

// Round 6
// 112.780 us; speedup vs baseline: 1.4094x; 1.1202x over previous
//
#include <hip/hip_runtime.h>
#include <hip/hip_bf16.h>
#include <stdint.h>

#define BB 8
#define LL 2048
#define DD 64

typedef short bf16x8 __attribute__((ext_vector_type(8)));  // 8 bf16 (4 VGPRs)
typedef float f32x4 __attribute__((ext_vector_type(4)));
typedef unsigned short ushort_t;
typedef __attribute__((address_space(1))) const unsigned int gas_u32;
typedef __attribute__((address_space(3))) unsigned int las_u32;

// ---- helpers --------------------------------------------------------------
__device__ __forceinline__ unsigned pk2(float lo, float hi) {
    union { __hip_bfloat162 h; unsigned u; } c;
    c.h = __float22bfloat162_rn(make_float2(lo, hi));   // v_cvt_pk_bf16_f32
    return c.u;
}
__device__ __forceinline__ float4 ld4(const float* __restrict__ p) {
    return *reinterpret_cast<const float4*>(p);
}
__device__ __forceinline__ bf16x8 cvt8f(float4 a, float4 b) {
    union { bf16x8 v; unsigned u[4]; } r;
    r.u[0] = pk2(a.x, a.y); r.u[1] = pk2(a.z, a.w);
    r.u[2] = pk2(b.x, b.y); r.u[3] = pk2(b.z, b.w);
    return r.v;
}
// async global->LDS, 16B per lane; LDS dst = wave-uniform base + lane*16 (HW)
__device__ __forceinline__ void glds16(const void* g, void* lds_base_uniform) {
    __builtin_amdgcn_global_load_lds((gas_u32*)g, (las_u32*)lds_base_uniform, 16, 0, 0);
}
// fallback-kernel helpers (round-2 proven)
__device__ __forceinline__ unsigned f2bf_u(float f) {
    union { float f; unsigned u; } v; v.f = f;
    return (v.u + 0x8000u) >> 16;
}
__device__ __forceinline__ bf16x8 cvt8(const float* __restrict__ p) {
    float4 a = ld4(p), b = ld4(p + 4);
    union { bf16x8 v; unsigned u[4]; } r;
    r.u[0] = f2bf_u(a.x) | (f2bf_u(a.y) << 16);
    r.u[1] = f2bf_u(a.z) | (f2bf_u(a.w) << 16);
    r.u[2] = f2bf_u(b.x) | (f2bf_u(b.y) << 16);
    r.u[3] = f2bf_u(b.z) | (f2bf_u(b.w) << 16);
    return r.v;
}

// ---- prep 1: K fp32 [b][k][d] -> bf16 same layout -------------------------
__global__ __launch_bounds__(256) void pack_k_bf16(const float* __restrict__ K,
                                                   ushort_t* __restrict__ Kb) {
    size_t i = ((size_t)blockIdx.x * 256 + threadIdx.x) * 8;
    float4 a = ld4(K + i), b = ld4(K + i + 4);
    uint4 o = { pk2(a.x, a.y), pk2(a.z, a.w), pk2(b.x, b.y), pk2(b.z, b.w) };
    *reinterpret_cast<uint4*>(Kb + i) = o;
}

// ---- prep 2: V fp32 [b][k][d] -> bf16 transposed [b][d][k] ----------------
__global__ __launch_bounds__(256) void transpose_v_bf(const float* __restrict__ V,
                                                      ushort_t* __restrict__ VT) {
    __shared__ float t[64][65];
    const int b  = blockIdx.x >> 5;
    const int kt = (blockIdx.x & 31) << 6;
    {
        const int r  = threadIdx.x >> 2;
        const int cq = (threadIdx.x & 3) << 4;
        const float* src = V + ((size_t)(b * LL + kt + r)) * DD + cq;
        #pragma unroll
        for (int i = 0; i < 4; ++i) {
            float4 v = ld4(src + 4 * i);
            t[r][cq + 4 * i + 0] = v.x; t[r][cq + 4 * i + 1] = v.y;
            t[r][cq + 4 * i + 2] = v.z; t[r][cq + 4 * i + 3] = v.w;
        }
    }
    __syncthreads();
    {
        const int d  = threadIdx.x >> 2;
        const int kq = (threadIdx.x & 3) << 4;
        ushort_t* dst = VT + ((size_t)(b * DD + d)) * LL + kt + kq;
        #pragma unroll
        for (int u = 0; u < 2; ++u) {
            uint4 o;
            o.x = pk2(t[kq + 8 * u + 0][d], t[kq + 8 * u + 1][d]);
            o.y = pk2(t[kq + 8 * u + 2][d], t[kq + 8 * u + 3][d]);
            o.z = pk2(t[kq + 8 * u + 4][d], t[kq + 8 * u + 5][d]);
            o.w = pk2(t[kq + 8 * u + 6][d], t[kq + 8 * u + 7][d]);
            *reinterpret_cast<uint4*>(dst + 8 * u) = o;
        }
    }
}

// ---- main attention kernel (m97-style LDS-staged, double-buffered) --------
// Block = 512 thr = 8 waves; 64 q per block; sweep all 2048 k in 32 tiles
// of 64 k. Grid = 8b x 32 qtiles = 256 blocks (1/CU). Waves split
// (q-subtile s=0..3) x (k-half h=0..1). Tiles staged to LDS via
// global_load_lds width 16, XOR-swizzled (granule col ^= row&7) so both
// ds_read_b128 fragment reads and DMA writes are conflict-free.
// Inner math identical to verified R3/R5: S^T = K*Q^T, exp*kmask,
// cross-quad bpermute P-transform, PV with V^T B-frags.
__global__ __launch_bounds__(512, 1) void attn5(
    const float* __restrict__ Q,
    const ushort_t* __restrict__ Kbf,
    const ushort_t* __restrict__ VTb,
    const int* __restrict__ qmask,
    const int* __restrict__ kmask,
    float* __restrict__ Out)
{
    const int tid  = threadIdx.x;
    const int wave = tid >> 6;         // 0..7
    const int lane = tid & 63;
    const int ln   = lane & 15;
    const int quad = lane >> 4;
    const int s    = wave >> 1;        // q-subtile 0..3
    const int h    = wave & 1;         // k-half 0..1

    const int b  = blockIdx.x >> 5;          // 8 batches
    const int q0 = (blockIdx.x & 31) << 6;   // 64 q per block

    __shared__ char  ldsbuf[2][16384];   // per buf: K tile 8KB, V tile 8KB
    __shared__ float kmf[LL];            // kmask as float, whole batch row
    __shared__ float Osum[64][68];
    __shared__ float Dsum[64];

    // prologue: zero accum, stage kmask row as floats
    for (int i = tid; i < 64 * 68; i += 512) (&Osum[0][0])[i] = 0.f;
    if (tid < 64) Dsum[tid] = 0.f;
    {
        int4 m = *reinterpret_cast<const int4*>(kmask + b * LL + tid * 4);
        float4 f = { (float)m.x, (float)m.y, (float)m.z, (float)m.w };
        *reinterpret_cast<float4*>(&kmf[tid * 4]) = f;
    }

    // Q B-frags (regs, once): q = q0+16s+ln, d = dh*32 + quad*8 + j
    bf16x8 qf[2];
    {
        const float* qp = Q + ((size_t)(b * LL + q0 + 16 * s + ln)) * DD + quad * 8;
        qf[0] = cvt8f(ld4(qp),      ld4(qp + 4));
        qf[1] = cvt8f(ld4(qp + 32), ld4(qp + 36));
    }

    // staging geometry: this lane stages 16B granule g of each 8KB half-tile
    const char* Kg = (const char*)Kbf + (size_t)b * LL * DD * 2;
    const char* Vg = (const char*)VTb + (size_t)b * DD * LL * 2;
    const int g  = wave * 64 + lane;           // 0..511
    const int rS = g >> 3;                     // row (k for K, d for V)
    const int cS = (g & 7) ^ (rS & 7);         // swizzled source granule col

    f32x4 Oacc[4] = {{0,0,0,0},{0,0,0,0},{0,0,0,0},{0,0,0,0}};
    float dsum = 0.f;

    const int src0 = ln + ((quad & 1) << 5);
    const int src1 = src0 + 16;
    const bool hi  = quad >= 2;

    #define STAGE(buf, k0)                                                        \
        do {                                                                      \
            glds16(Kg + (size_t)((k0) + rS) * 128 + cS * 16,                      \
                   &ldsbuf[buf][wave * 1024]);                                    \
            glds16(Vg + (size_t)rS * (LL * 2) + (k0) * 2 + cS * 16,               \
                   &ldsbuf[buf][8192 + wave * 1024]);                             \
        } while (0)

    STAGE(0, 0);

    for (int i = 0; i < 32; ++i) {
        __syncthreads();   // implicit vmcnt(0): tile i staging complete; buf (i+1)&1 free
        const int knext = ((i + 1) & 31) * 64;   // wrap at end: harmless restage
        STAGE((i + 1) & 1, knext);

        const int   k0 = i * 64;
        const char* LK = ldsbuf[i & 1];
        const char* LV = ldsbuf[i & 1] + 8192;

        // K A-frags from LDS (swizzled), rows 32h..32h+31
        bf16x8 kf[2][2];
        #pragma unroll
        for (int tt = 0; tt < 2; ++tt) {
            const int r = 16 * (2 * h + tt) + ln;
            #pragma unroll
            for (int dh = 0; dh < 2; ++dh) {
                const int c = (dh * 4 + quad) ^ (ln & 7);
                kf[tt][dh] = *reinterpret_cast<const bf16x8*>(LK + r * 128 + c * 16);
            }
        }
        // V B-frags from LDS (swizzled): d = db*16+ln, k-local = 32h+quad*8+j
        bf16x8 vf[4];
        const int cv = (4 * h + quad) ^ (ln & 7);
        #pragma unroll
        for (int db = 0; db < 4; ++db) {
            const int d = db * 16 + ln;
            vf[db] = *reinterpret_cast<const bf16x8*>(LV + d * 128 + cv * 16);
        }

        // S^T = K·Q^T for the wave's 32-k half; exp*mask; pack
        unsigned w[2][2];
        #pragma unroll
        for (int tt = 0; tt < 2; ++tt) {
            f32x4 acc = (f32x4){0.f, 0.f, 0.f, 0.f};
            acc = __builtin_amdgcn_mfma_f32_16x16x32_bf16(kf[tt][0], qf[0], acc, 0, 0, 0);
            acc = __builtin_amdgcn_mfma_f32_16x16x32_bf16(kf[tt][1], qf[1], acc, 0, 0, 0);
            const float4 km = *reinterpret_cast<const float4*>(
                &kmf[k0 + 16 * (2 * h + tt) + 4 * quad]);
            float e0 = __expf(acc[0] * 0.125f) * km.x;
            float e1 = __expf(acc[1] * 0.125f) * km.y;
            float e2 = __expf(acc[2] * 0.125f) * km.z;
            float e3 = __expf(acc[3] * 0.125f) * km.w;
            dsum += (e0 + e1) + (e2 + e3);
            w[tt][0] = pk2(e0, e1);
            w[tt][1] = pk2(e2, e3);
        }
        // P^T(C-layout) -> P(A-layout): cross-quad permutation (R3/R5-verified)
        union { bf16x8 v; unsigned u[4]; } pf;
        {
            unsigned a0 = __shfl(w[0][0], src0), b0 = __shfl(w[1][0], src0);
            unsigned a1 = __shfl(w[0][1], src0), b1 = __shfl(w[1][1], src0);
            unsigned a2 = __shfl(w[0][0], src1), b2 = __shfl(w[1][0], src1);
            unsigned a3 = __shfl(w[0][1], src1), b3 = __shfl(w[1][1], src1);
            pf.u[0] = hi ? b0 : a0;
            pf.u[1] = hi ? b1 : a1;
            pf.u[2] = hi ? b2 : a2;
            pf.u[3] = hi ? b3 : a3;
        }
        #pragma unroll
        for (int db = 0; db < 4; ++db)
            Oacc[db] = __builtin_amdgcn_mfma_f32_16x16x32_bf16(pf.v, vf[db], Oacc[db], 0, 0, 0);
    }
    #undef STAGE

    // den: reduce over quads (q = ln within subtile s)
    {
        float v = dsum;
        v += __shfl_xor(v, 16);
        v += __shfl_xor(v, 32);
        dsum = v;
    }

    // combine (s,h) wave partials via LDS atomics (R5-verified epilogue)
    #pragma unroll
    for (int db = 0; db < 4; ++db)
        #pragma unroll
        for (int r = 0; r < 4; ++r)
            atomicAdd(&Osum[16 * s + quad * 4 + r][db * 16 + ln], Oacc[db][r]);
    if (quad == 0) atomicAdd(&Dsum[16 * s + ln], dsum);
    __syncthreads();

    // normalize by max(den,1), apply q_mask, store fp32
    const int q  = tid >> 3;           // 0..63
    const int d0 = (tid & 7) << 3;     // 0..56
    float dn  = Dsum[q];
    float inv = 1.0f / fmaxf(dn, 1.0f);
    float sc  = qmask[b * LL + q0 + q] ? inv : 0.0f;
    f32x4 o0 = *reinterpret_cast<const f32x4*>(&Osum[q][d0])     * sc;
    f32x4 o1 = *reinterpret_cast<const f32x4*>(&Osum[q][d0 + 4]) * sc;
    float* op = Out + ((size_t)(b * LL + q0 + q)) * DD + d0;
    *reinterpret_cast<f32x4*>(op)     = o0;
    *reinterpret_cast<f32x4*>(op + 4) = o1;
}

// ---- fallback (round-2 kernel, used only if ws too small) -----------------
__global__ __launch_bounds__(256, 4) void attn_mfma(
    const float* __restrict__ Q, const float* __restrict__ K,
    const float* __restrict__ V, const int* __restrict__ qmask,
    const int* __restrict__ kmask, float* __restrict__ Out)
{
    const int tid  = threadIdx.x;
    const int wave = tid >> 6;
    const int lane = tid & 63;
    const int n    = lane & 15;
    const int quad = lane >> 4;
    const int bx = blockIdx.x;
    const int b  = bx >> 7;
    const int q0 = (bx & 127) << 4;
    __shared__ float Pl[4][576];
    __shared__ float Opart[4][16][68];
    __shared__ float Denp[4][16];
    const float* Qp = Q + ((size_t)(b * LL + q0 + n)) * DD + quad * 8;
    bf16x8 qf0 = cvt8(Qp);
    bf16x8 qf1 = cvt8(Qp + 32);
    const float* Kb = K + ((size_t)(b * LL) + n) * DD + quad * 8;
    const float* Vb = V + ((size_t)(b * LL) + quad * 8) * DD + n;
    const int* kmb = kmask + b * LL;
    f32x4 Oacc[4] = {{0,0,0,0},{0,0,0,0},{0,0,0,0},{0,0,0,0}};
    float den[4]  = {0.f, 0.f, 0.f, 0.f};
    float*       pw = &Pl[wave][144 * (n >> 3) + 36 * quad + (n & 7)];
    const float* pr = &Pl[wave][9 * lane];
    const int kbeg = wave * (LL / 4);
    const int kend = kbeg + (LL / 4);
    for (int k0 = kbeg; k0 < kend; k0 += 32) {
        const float* krow = Kb + (size_t)k0 * DD;
        bf16x8 kA0 = cvt8(krow);
        bf16x8 kA1 = cvt8(krow + 32);
        bf16x8 kB0 = cvt8(krow + 16 * DD);
        bf16x8 kB1 = cvt8(krow + 16 * DD + 32);
        f32x4 z = {0.f, 0.f, 0.f, 0.f};
        f32x4 S0 = __builtin_amdgcn_mfma_f32_16x16x32_bf16(qf0, kA0, z, 0, 0, 0);
        S0 = __builtin_amdgcn_mfma_f32_16x16x32_bf16(qf1, kA1, S0, 0, 0, 0);
        f32x4 S1 = __builtin_amdgcn_mfma_f32_16x16x32_bf16(qf0, kB0, z, 0, 0, 0);
        S1 = __builtin_amdgcn_mfma_f32_16x16x32_bf16(qf1, kB1, S1, 0, 0, 0);
        float km0 = (float)kmb[k0 + n];
        float km1 = (float)kmb[k0 + 16 + n];
        #pragma unroll
        for (int r = 0; r < 4; ++r) {
            float e0 = __expf(S0[r] * 0.125f) * km0;
            float e1 = __expf(S1[r] * 0.125f) * km1;
            den[r] += e0 + e1;
            pw[9 * r]       = e0;
            pw[288 + 9 * r] = e1;
        }
        __builtin_amdgcn_wave_barrier();
        float pv[8];
        #pragma unroll
        for (int j = 0; j < 8; ++j) pv[j] = pr[j];
        __builtin_amdgcn_wave_barrier();
        union { bf16x8 v; unsigned u[4]; } pf;
        #pragma unroll
        for (int j = 0; j < 4; ++j)
            pf.u[j] = f2bf_u(pv[2 * j]) | (f2bf_u(pv[2 * j + 1]) << 16);
        const float* vrow = Vb + (size_t)k0 * DD;
        #pragma unroll
        for (int db = 0; db < 4; ++db) {
            union { bf16x8 v; unsigned u[4]; } vfr;
            #pragma unroll
            for (int jj = 0; jj < 4; ++jj) {
                unsigned lo  = f2bf_u(vrow[(2 * jj) * DD + db * 16]);
                unsigned hi2 = f2bf_u(vrow[(2 * jj + 1) * DD + db * 16]);
                vfr.u[jj] = lo | (hi2 << 16);
            }
            Oacc[db] = __builtin_amdgcn_mfma_f32_16x16x32_bf16(pf.v, vfr.v, Oacc[db], 0, 0, 0);
        }
    }
    #pragma unroll
    for (int r = 0; r < 4; ++r) {
        float v = den[r];
        v += __shfl_xor(v, 1); v += __shfl_xor(v, 2);
        v += __shfl_xor(v, 4); v += __shfl_xor(v, 8);
        den[r] = v;
    }
    #pragma unroll
    for (int db = 0; db < 4; ++db)
        #pragma unroll
        for (int r = 0; r < 4; ++r)
            Opart[wave][quad * 4 + r][db * 16 + n] = Oacc[db][r];
    if (n == 0) {
        #pragma unroll
        for (int r = 0; r < 4; ++r) Denp[wave][quad * 4 + r] = den[r];
    }
    __syncthreads();
    const int q  = tid >> 4;
    const int d0 = (tid & 15) * 4;
    f32x4 sum = *reinterpret_cast<const f32x4*>(&Opart[0][q][d0]);
    sum += *reinterpret_cast<const f32x4*>(&Opart[1][q][d0]);
    sum += *reinterpret_cast<const f32x4*>(&Opart[2][q][d0]);
    sum += *reinterpret_cast<const f32x4*>(&Opart[3][q][d0]);
    float dn  = Denp[0][q] + Denp[1][q] + Denp[2][q] + Denp[3][q];
    float inv = 1.0f / fmaxf(dn, 1.0f);
    float s   = qmask[b * LL + q0 + q] ? inv : 0.0f;
    f32x4 o   = sum * s;
    float* op = Out + ((size_t)(b * LL + q0 + q)) * DD + d0;
    *reinterpret_cast<f32x4*>(op) = o;
}

extern "C" void kernel_launch(void* const* d_in, const int* in_sizes, int n_in,
                              void* d_out, int out_size, void* d_ws, size_t ws_size,
                              hipStream_t stream) {
    (void)in_sizes; (void)n_in; (void)out_size;
    const float* Q  = (const float*)d_in[0];
    const float* K  = (const float*)d_in[1];
    const float* V  = (const float*)d_in[2];
    const int* qm   = (const int*)d_in[3];
    const int* km   = (const int*)d_in[4];
    float* Out      = (float*)d_out;

    const size_t elems    = (size_t)BB * LL * DD;            // 1,048,576
    const size_t ws_need  = elems * 2 * sizeof(ushort_t);    // 4 MiB
    if (ws_size >= ws_need && d_ws != nullptr) {
        ushort_t* Kbf = (ushort_t*)d_ws;
        ushort_t* VTb = Kbf + elems;
        pack_k_bf16   <<<dim3(elems / (256 * 8)), dim3(256), 0, stream>>>(K, Kbf);
        transpose_v_bf<<<dim3(BB * (LL / 64)),    dim3(256), 0, stream>>>(V, VTb);
        attn5<<<dim3(BB * (LL / 64)), dim3(512), 0, stream>>>(Q, Kbf, VTb, qm, km, Out);
    } else {
        attn_mfma<<<dim3(BB * (LL / 16)), dim3(256), 0, stream>>>(Q, K, V, qm, km, Out);
    }
}